// Round 1
// baseline (57.053 us; speedup 1.0000x reference)
//
#include <hip/hip_runtime.h>

// Problem constants (fixed by the reference's setup_inputs)
#define IN_F   256
#define N_ASS  4096
#define OUT_F  256
#define BATCH  128
#define ASS0   256      // first associative node index
#define OUT0   4352     // first output node index (IN_F + N_ASS)

// Workspace layout (fp32):
//   W1d : [N_ASS][IN_F]   @ 0                      (4 MB)  dense input->assoc weights
//   W2d : [OUT_F][N_ASS]  @ N_ASS*IN_F             (4 MB)  dense assoc->output weights
//   acc : [BATCH][N_ASS]  @ N_ASS*IN_F+OUT_F*N_ASS (2 MB)  hop-1 activations

__global__ void scatter1_kernel(const int* __restrict__ src, const int* __restrict__ dst,
                                const float* __restrict__ w, float* __restrict__ W1d, int E) {
    int e = blockIdx.x * blockDim.x + threadIdx.x;
    if (e < E) {
        // dst in [ASS0, ASS0+N_ASS); unique (src,dst) pairs -> plain store
        W1d[(dst[e] - ASS0) * IN_F + src[e]] = w[e];
    }
}

__global__ void scatter2_kernel(const int* __restrict__ src, const int* __restrict__ dst,
                                const float* __restrict__ w, float* __restrict__ W2d, int E) {
    int e = blockIdx.x * blockDim.x + threadIdx.x;
    if (e < E) {
        int d = dst[e];
        // only edges into output nodes matter for the final result
        if (d >= OUT0) {
            W2d[(d - OUT0) * N_ASS + (src[e] - ASS0)] = w[e];
        }
    }
}

// C[M][N] (+)= A[M][K] * B[N][K]^T  (both row-major, "NT" dot-product GEMM)
// BM=BN=64, BK=16, 256 threads, 4x4 micro-tile per thread.
// blockIdx.z selects a K-chunk of size kChunk; ATOMIC=true accumulates via atomicAdd.
template<bool ATOMIC>
__global__ __launch_bounds__(256) void gemm_nt(const float* __restrict__ A,
                                               const float* __restrict__ B,
                                               float* __restrict__ C,
                                               int M, int N, int K, int kChunk) {
    constexpr int BM = 64, BN = 64, BK = 16;
    __shared__ __align__(16) float As[BK][BM + 4];   // +4 pad: stride 272B (16B-aligned, bank-safe)
    __shared__ __align__(16) float Bs[BK][BN + 4];

    const int tid = threadIdx.x;
    const int tx = tid & 15;   // N direction (16)
    const int ty = tid >> 4;   // M direction (16)
    const int m0 = blockIdx.x * BM;
    const int n0 = blockIdx.y * BN;
    const int kBeg = blockIdx.z * kChunk;
    const int kEnd = kBeg + kChunk;

    // loader mapping: 256 threads x one float4 covers a 64x16 fp32 tile
    const int lr = tid >> 2;          // row in tile, 0..63
    const int lc = (tid & 3) * 4;     // k-offset in tile, {0,4,8,12}

    float acc[4][4] = {};

    for (int k0 = kBeg; k0 < kEnd; k0 += BK) {
        float4 av = *(const float4*)(A + (size_t)(m0 + lr) * K + k0 + lc);
        float4 bv = *(const float4*)(B + (size_t)(n0 + lr) * K + k0 + lc);
        __syncthreads();   // protect previous iteration's LDS reads
        As[lc + 0][lr] = av.x; As[lc + 1][lr] = av.y; As[lc + 2][lr] = av.z; As[lc + 3][lr] = av.w;
        Bs[lc + 0][lr] = bv.x; Bs[lc + 1][lr] = bv.y; Bs[lc + 2][lr] = bv.z; Bs[lc + 3][lr] = bv.w;
        __syncthreads();

        #pragma unroll
        for (int k = 0; k < BK; ++k) {
            float4 a4 = *(const float4*)&As[k][ty * 4];
            float4 b4 = *(const float4*)&Bs[k][tx * 4];
            float a[4] = {a4.x, a4.y, a4.z, a4.w};
            float b[4] = {b4.x, b4.y, b4.z, b4.w};
            #pragma unroll
            for (int i = 0; i < 4; ++i)
                #pragma unroll
                for (int j = 0; j < 4; ++j)
                    acc[i][j] = fmaf(a[i], b[j], acc[i][j]);
        }
    }

    #pragma unroll
    for (int i = 0; i < 4; ++i) {
        const int m = m0 + ty * 4 + i;
        if (ATOMIC) {
            #pragma unroll
            for (int j = 0; j < 4; ++j)
                atomicAdd(&C[(size_t)m * N + n0 + tx * 4 + j], acc[i][j]);
        } else {
            float4 v = make_float4(acc[i][0], acc[i][1], acc[i][2], acc[i][3]);
            *(float4*)&C[(size_t)m * N + n0 + tx * 4] = v;
        }
    }
}

extern "C" void kernel_launch(void* const* d_in, const int* in_sizes, int n_in,
                              void* d_out, int out_size, void* d_ws, size_t ws_size,
                              hipStream_t stream) {
    const float* x      = (const float*)d_in[0];   // [BATCH][IN_F]
    const float* w_in   = (const float*)d_in[1];   // [E_in]
    const float* w_ass  = (const float*)d_in[2];   // [E_ass]
    const int*   in_src = (const int*)d_in[3];
    const int*   in_dst = (const int*)d_in[4];
    const int*   a_src  = (const int*)d_in[5];
    const int*   a_dst  = (const int*)d_in[6];
    const int E_in  = in_sizes[3];
    const int E_ass = in_sizes[5];

    float* W1d = (float*)d_ws;                       // [N_ASS][IN_F]
    float* W2d = W1d + (size_t)N_ASS * IN_F;         // [OUT_F][N_ASS]
    float* acc = W2d + (size_t)OUT_F * N_ASS;        // [BATCH][N_ASS]
    float* out = (float*)d_out;                      // [BATCH][OUT_F]

    // zero dense weight buffers + output (output accumulated atomically)
    hipMemsetAsync(d_ws, 0, (size_t)(N_ASS * IN_F + OUT_F * N_ASS) * sizeof(float), stream);
    hipMemsetAsync(d_out, 0, (size_t)BATCH * OUT_F * sizeof(float), stream);

    scatter1_kernel<<<(E_in + 255) / 256, 256, 0, stream>>>(in_src, in_dst, w_in, W1d, E_in);
    scatter2_kernel<<<(E_ass + 255) / 256, 256, 0, stream>>>(a_src, a_dst, w_ass, W2d, E_ass);

    // GEMM1: acc[128][4096] = x[128][256] * W1d[4096][256]^T   (single K chunk)
    dim3 g1(BATCH / 64, N_ASS / 64, 1);
    gemm_nt<false><<<g1, 256, 0, stream>>>(x, W1d, acc, BATCH, N_ASS, IN_F, IN_F);

    // GEMM2: out[128][256] += acc[128][4096] * W2d[256][4096]^T  (split-K = 16, atomic)
    dim3 g2(BATCH / 64, OUT_F / 64, 16);
    gemm_nt<true><<<g2, 256, 0, stream>>>(acc, W2d, out, BATCH, OUT_F, N_ASS, N_ASS / 16);
}

// Round 2
// 44.289 us; speedup vs baseline: 1.2882x; 1.2882x over previous
//
#include <hip/hip_runtime.h>

// Problem constants (fixed by the reference's setup_inputs)
#define IN_F   256
#define N_ASS  4096
#define OUT_F  256
#define BATCH  128
#define ASS0   256      // first associative node index
#define OUT0   4352     // first output node index (IN_F + N_ASS)
#define SPLITK 32       // GEMM2 split-K factor

// Workspace layout (fp32):
//   W1d : [N_ASS][IN_F]   @ 0                       (4 MB)  dense input->assoc weights
//         -- after GEMM1, this region is reused as P[SPLITK][BATCH][OUT_F] (4 MB)
//   W2d : [OUT_F][N_ASS]  @ N_ASS*IN_F              (4 MB)  dense assoc->output weights
//   acc : [BATCH][N_ASS]  @ N_ASS*IN_F+OUT_F*N_ASS  (2 MB)  hop-1 activations

__global__ void zero_kernel(float4* __restrict__ p, int n4) {
    int i = blockIdx.x * blockDim.x + threadIdx.x;
    if (i < n4) p[i] = make_float4(0.f, 0.f, 0.f, 0.f);
}

__global__ void scatter1_kernel(const int* __restrict__ src, const int* __restrict__ dst,
                                const float* __restrict__ w, float* __restrict__ W1d, int E) {
    int e = blockIdx.x * blockDim.x + threadIdx.x;
    if (e < E) {
        // dst in [ASS0, ASS0+N_ASS); (src,dst) pairs unique -> plain store
        W1d[(dst[e] - ASS0) * IN_F + src[e]] = w[e];
    }
}

__global__ void scatter2_kernel(const int* __restrict__ src, const int* __restrict__ dst,
                                const float* __restrict__ w, float* __restrict__ W2d, int E) {
    int e = blockIdx.x * blockDim.x + threadIdx.x;
    if (e < E) {
        int d = dst[e];
        // only edges into output nodes matter for the final result
        if (d >= OUT0) {
            W2d[(d - OUT0) * N_ASS + (src[e] - ASS0)] = w[e];
        }
    }
}

// C[M][N] = A[M][K(chunk)] * B[N][K(chunk)]^T  (row-major, "NT" dot-product GEMM)
// BN fixed 64, BM in {32,64}. 256 threads. Per-thread micro-tile (BM/16) x 4.
// SPLITK_STORE: write this block's K-chunk partial to C + z*M*N (non-atomic).
template<int BM, bool SPLITK_STORE>
__global__ __launch_bounds__(256) void gemm_nt(const float* __restrict__ A,
                                               const float* __restrict__ B,
                                               float* __restrict__ C,
                                               int M, int N, int K, int kChunk) {
    constexpr int BN = 64, BK = 16;
    constexpr int TM = BM / 16;          // 2 or 4 rows per thread
    __shared__ __align__(16) float As[BK][BM + 4];
    __shared__ __align__(16) float Bs[BK][BN + 4];

    const int tid = threadIdx.x;
    const int tx = tid & 15;             // N direction
    const int ty = tid >> 4;             // M direction
    const int m0 = blockIdx.x * BM;
    const int n0 = blockIdx.y * BN;
    const int kBeg = blockIdx.z * kChunk;
    const int kEnd = kBeg + kChunk;

    // loader: thread t handles float4 at row (t>>2), k-offset (t&3)*4
    const int lr = tid >> 2;             // 0..63
    const int lc = (tid & 3) * 4;
    const bool hasA = (lr < BM);

    float acc[TM][4] = {};

    for (int k0 = kBeg; k0 < kEnd; k0 += BK) {
        float4 av, bv;
        if (hasA) av = *(const float4*)(A + (size_t)(m0 + lr) * K + k0 + lc);
        bv = *(const float4*)(B + (size_t)(n0 + lr) * K + k0 + lc);
        __syncthreads();   // protect previous iteration's LDS reads
        if (hasA) {
            As[lc + 0][lr] = av.x; As[lc + 1][lr] = av.y;
            As[lc + 2][lr] = av.z; As[lc + 3][lr] = av.w;
        }
        Bs[lc + 0][lr] = bv.x; Bs[lc + 1][lr] = bv.y;
        Bs[lc + 2][lr] = bv.z; Bs[lc + 3][lr] = bv.w;
        __syncthreads();

        #pragma unroll
        for (int k = 0; k < BK; ++k) {
            float4 b4 = *(const float4*)&Bs[k][tx * 4];
            float b[4] = {b4.x, b4.y, b4.z, b4.w};
            float a[TM];
            if constexpr (TM == 4) {
                float4 a4 = *(const float4*)&As[k][ty * 4];
                a[0] = a4.x; a[1] = a4.y; a[2] = a4.z; a[3] = a4.w;
            } else {
                float2 a2 = *(const float2*)&As[k][ty * 2];
                a[0] = a2.x; a[1] = a2.y;
            }
            #pragma unroll
            for (int i = 0; i < TM; ++i)
                #pragma unroll
                for (int j = 0; j < 4; ++j)
                    acc[i][j] = fmaf(a[i], b[j], acc[i][j]);
        }
    }

    float* Cb = SPLITK_STORE ? C + (size_t)blockIdx.z * M * N : C;
    #pragma unroll
    for (int i = 0; i < TM; ++i) {
        const int m = m0 + ty * TM + i;
        float4 v = make_float4(acc[i][0], acc[i][1], acc[i][2], acc[i][3]);
        *(float4*)&Cb[(size_t)m * N + n0 + tx * 4] = v;
    }
}

// out[i] = sum_s P[s][i], i over M*N
__global__ void reduce_kernel(const float* __restrict__ P, float* __restrict__ out, int MN) {
    int i = blockIdx.x * blockDim.x + threadIdx.x;
    if (i < MN) {
        float s = 0.f;
        #pragma unroll
        for (int j = 0; j < SPLITK; ++j) s += P[(size_t)j * MN + i];
        out[i] = s;
    }
}

extern "C" void kernel_launch(void* const* d_in, const int* in_sizes, int n_in,
                              void* d_out, int out_size, void* d_ws, size_t ws_size,
                              hipStream_t stream) {
    const float* x      = (const float*)d_in[0];   // [BATCH][IN_F]
    const float* w_in   = (const float*)d_in[1];   // [E_in]
    const float* w_ass  = (const float*)d_in[2];   // [E_ass]
    const int*   in_src = (const int*)d_in[3];
    const int*   in_dst = (const int*)d_in[4];
    const int*   a_src  = (const int*)d_in[5];
    const int*   a_dst  = (const int*)d_in[6];
    const int E_in  = in_sizes[3];
    const int E_ass = in_sizes[5];

    float* W1d = (float*)d_ws;                       // [N_ASS][IN_F]; later P[SPLITK][BATCH][OUT_F]
    float* W2d = W1d + (size_t)N_ASS * IN_F;         // [OUT_F][N_ASS]
    float* acc = W2d + (size_t)OUT_F * N_ASS;        // [BATCH][N_ASS]
    float* P   = W1d;                                // alias: W1d dead after GEMM1
    float* out = (float*)d_out;                      // [BATCH][OUT_F]

    // zero dense weight buffers (8 MB) with a properly-sized fill kernel
    const int n4 = (N_ASS * IN_F + OUT_F * N_ASS) / 4;
    zero_kernel<<<(n4 + 255) / 256, 256, 0, stream>>>((float4*)d_ws, n4);

    scatter1_kernel<<<(E_in + 255) / 256, 256, 0, stream>>>(in_src, in_dst, w_in, W1d, E_in);
    scatter2_kernel<<<(E_ass + 255) / 256, 256, 0, stream>>>(a_src, a_dst, w_ass, W2d, E_ass);

    // GEMM1: acc[128][4096] = x[128][256] * W1d[4096][256]^T   (256 blocks)
    dim3 g1(BATCH / 32, N_ASS / 64, 1);
    gemm_nt<32, false><<<g1, 256, 0, stream>>>(x, W1d, acc, BATCH, N_ASS, IN_F, IN_F);

    // GEMM2: P[z] = acc[128][4096/SPLITK slice] * W2d^T slice   (2x4x32 = 256 blocks)
    dim3 g2(BATCH / 64, OUT_F / 64, SPLITK);
    gemm_nt<64, true><<<g2, 256, 0, stream>>>(acc, W2d, P, BATCH, OUT_F, N_ASS, N_ASS / SPLITK);

    // out = sum over SPLITK partials
    const int MN = BATCH * OUT_F;
    reduce_kernel<<<(MN + 255) / 256, 256, 0, stream>>>(P, out, MN);
}